// Round 1
// 111.830 us; speedup vs baseline: 1.0442x; 1.0442x over previous
//
#include <hip/hip_runtime.h>

#define NPTS 8192
#define NTOT 16384
#define KNB 11
#define CAP 16
#define MARG 9.0f
#define MAXM 8192

typedef __attribute__((ext_vector_type(8))) short short8;
typedef __attribute__((ext_vector_type(4))) float f32x4;

__device__ __forceinline__ unsigned short f2bf(float x) {
  union { float f; unsigned u; } v; v.f = x;
  unsigned r = v.u + 0x7FFFu + ((v.u >> 16) & 1u);
  return (unsigned short)(r >> 16);
}

__device__ __forceinline__ float sigm(float x) { return 1.f / (1.f + expf(-x)); }

// ---------------- K1: f = (p^T*W1 + b1)*W2 + b2 ; sq/sq32 ; bf16 prefilter copy ----
// 256 blocks x 256 threads: 64 points/block, wave w handles dims e0=w*16..+16.
// Two chained 64x64 GEMMs; t staged through a +1-padded LDS transpose.
// W1/W2 rows are wave-uniform -> s_load path (same trick as the old W12 reads).
// Also zeroes cnt (64 rows/block) and the coupled-list counter (block 0).
__global__ __launch_bounds__(256) void k1_encode(
    const float* __restrict__ p,      // [2][64][NPTS]
    const float* __restrict__ W1,     // [64][64]
    const float* __restrict__ b1,     // [64]
    const float* __restrict__ W2,     // [64][64]
    const float* __restrict__ b2,     // [64]
    float* __restrict__ f32f,         // [NTOT][64]
    unsigned short* __restrict__ fpre,// [NTOT][32] bf16 (dims 0..31)
    float* __restrict__ sq,           // [NTOT] full 64-dim |f|^2
    float* __restrict__ sq32,         // [NTOT] dims 0..31 |f|^2
    unsigned* __restrict__ cnt,       // [NTOT] candidate counters (zeroed here)
    int* __restrict__ lctr) {         // coupled-list counter (zeroed here)
  __shared__ float sp[64 * 64];       // 16 KB: sp[d*64 + n_local]
  __shared__ float st[64 * 65];       // 16.25 KB: st[n_local*65 + d] (+1 pad)
  __shared__ float sPart[4][64];
  int t = threadIdx.x, lane = t & 63;
  int w = __builtin_amdgcn_readfirstlane(t >> 6);
  int e0 = w * 16;                          // wave-uniform -> scalar loads
  int base = blockIdx.x * 64;
  int b = base >> 13, n0 = base & (NPTS - 1);
  const float* pb = p + (size_t)b * 64 * NPTS + n0;

  if (w == 0) cnt[base + lane] = 0u;        // 256 blocks x 64 = all NTOT rows
  if (base == 0 && t == 0) *lctr = 0;

  // stage p tile: 64 d-rows x 64 points, coalesced uint4
  int row = t >> 4, chunk = t & 15;
#pragma unroll
  for (int k = 0; k < 4; ++k) {
    int r = k * 16 + row;
    uint4 v = *(const uint4*)(pb + (size_t)r * NPTS + chunk * 4);
    *(uint4*)(sp + r * 64 + chunk * 4) = v;
  }
  __syncthreads();

  // GEMM1: t[n][e] = b1[e] + sum_d p[d][n]*W1[d][e]
  float tt[16];
#pragma unroll
  for (int j = 0; j < 16; ++j) tt[j] = b1[e0 + j];
#pragma unroll 8
  for (int d = 0; d < 64; ++d) {
    float pd = sp[d * 64 + lane];
#pragma unroll
    for (int j = 0; j < 16; ++j)
      tt[j] = fmaf(pd, W1[d * 64 + e0 + j], tt[j]);
  }
  // transpose t into LDS: st[point][dim], pad 65 -> conflict-free both ways
#pragma unroll
  for (int j = 0; j < 16; ++j) st[lane * 65 + e0 + j] = tt[j];
  __syncthreads();

  // GEMM2: f[n][e] = b2[e] + sum_d t[n][d]*W2[d][e]
  float f[16];
#pragma unroll
  for (int j = 0; j < 16; ++j) f[j] = b2[e0 + j];
#pragma unroll 8
  for (int d = 0; d < 64; ++d) {
    float td = st[lane * 65 + d];
#pragma unroll
    for (int j = 0; j < 16; ++j)
      f[j] = fmaf(td, W2[d * 64 + e0 + j], f[j]);
  }

  float s = 0.f;
#pragma unroll
  for (int j = 0; j < 16; ++j) s = fmaf(f[j], f[j], s);
  sPart[w][lane] = s;
  __syncthreads();
  if (w == 0) {
    float s32 = sPart[0][lane] + sPart[1][lane];
    float s64 = s32 + (sPart[2][lane] + sPart[3][lane]);
    sq32[base + lane] = s32;
    sq[base + lane] = s64;
  }

  f32x4* o4 = (f32x4*)(f32f + (size_t)(base + lane) * 64 + e0);
#pragma unroll
  for (int jj = 0; jj < 4; ++jj) {
    f32x4 v; v[0] = f[4 * jj]; v[1] = f[4 * jj + 1]; v[2] = f[4 * jj + 2]; v[3] = f[4 * jj + 3];
    o4[jj] = v;
  }
  if (w < 2) {                               // dims 0..31 -> bf16 prefilter
    unsigned* ob = (unsigned*)(fpre + (size_t)(base + lane) * 32 + e0);
#pragma unroll
    for (int jj = 0; jj < 8; ++jj) {
      unsigned lo = f2bf(f[2 * jj]);
      unsigned hi = f2bf(f[2 * jj + 1]);
      ob[jj] = lo | (hi << 16);
    }
  }
}

// ---------------- K2: 32-dim prefilter Gram, triangle-symmetric ----
// 1056 blocks = 2 x 528 (lower-triangle incl diag of 32x32 256-blocks).
// Hot: per tile 1 ds_read + 4 MFMA + EXACT per-row/col margin test -> SGPR hitmask.
// Cold (once, after loop): recompute only hit tiles (diag: 4/16; off-diag: ~never).
// NEW: the capture whose atomicAdd returns old==1 is the row's 1->2 transition:
// append that row to the compact coupled list (consumed by kt_iter, no 16K scan).
__global__ __launch_bounds__(256) void k2_gram_select(
    const unsigned short* __restrict__ fpre, // [NTOT][32]
    const float* __restrict__ sq32,          // [NTOT]
    unsigned* __restrict__ cnt,              // [NTOT]
    unsigned* __restrict__ cand,             // [NTOT][CAP]
    int* __restrict__ lctr,                  // coupled-list counter
    int* __restrict__ list) {                // [MAXM] coupled rows (global ids)
  __shared__ uint4 sB[1024];                 // 16 KB panel, XOR-swizzled
  int bid = blockIdx.x;
  int b = (bid >= 528) ? 1 : 0;
  int rem = bid - b * 528;
  int band = (int)((sqrtf(8.f * (float)rem + 1.f) - 1.f) * 0.5f);
  if (((band + 1) * (band + 2)) / 2 <= rem) band++;
  else if ((band * (band + 1)) / 2 > rem) band--;
  int seg = rem - (band * (band + 1)) / 2;

  int t = threadIdx.x;
  int lane = t & 63;
  int arow = lane & 15;
  int q = lane >> 4;
  int wave = t >> 6;
  int rowbase = band * 256 + wave * 64;
  int cbase = seg * 256;
  const unsigned short* fb = fpre + (size_t)b * NPTS * 32;
  const float* s32b = sq32 + b * NPTS;

  // ---- prologue: all global loads, then ONE barrier ----
  const uint4* gsrc = (const uint4*)fb + (size_t)seg * 1024;
  uint4 v[4];
#pragma unroll
  for (int k = 0; k < 4; ++k) v[k] = gsrc[t + k * 256];

  short8 afrag[4];
#pragma unroll
  for (int tr = 0; tr < 4; ++tr)
    afrag[tr] = *(const short8*)(fb + (size_t)(rowbase + tr * 16 + arow) * 32 + q * 8);

  f32x4 srq[4], hh[4];
#pragma unroll
  for (int tr = 0; tr < 4; ++tr) {
    srq[tr] = *(const f32x4*)(s32b + rowbase + tr * 16 + (q << 2));
    hh[tr] = 0.5f * srq[tr];
  }
  float thrc[16];                            // per-lane column threshold
#pragma unroll
  for (int cc = 0; cc < 4; ++cc)
#pragma unroll
    for (int tc = 0; tc < 4; ++tc)
      thrc[cc * 4 + tc] = 0.5f * s32b[cbase + cc * 64 + tc * 16 + arow] - 0.5f * MARG;

#pragma unroll
  for (int k = 0; k < 4; ++k) {
    int c = t + k * 256;
    int r = c >> 2, qq = c & 3;
    sB[r * 4 + (qq ^ (r & 3))] = v[k];
  }
  __syncthreads();   // the ONLY barrier

  // ---- hot pass: MFMA + exact margin test, hit tiles -> SGPR mask ----
  f32x4 z4 = {0.f, 0.f, 0.f, 0.f};
  unsigned hitmask = 0u;
#pragma unroll
  for (int cc = 0; cc < 4; ++cc)
#pragma unroll
    for (int tc = 0; tc < 4; ++tc) {
      int e = cc * 4 + tc;
      int rl = cc * 64 + tc * 16 + arow;
      short8 bf = *(const short8*)&sB[rl * 4 + (q ^ (rl & 3))];
      f32x4 a0 = __builtin_amdgcn_mfma_f32_16x16x32_bf16(afrag[0], bf, z4, 0, 0, 0);
      f32x4 a1 = __builtin_amdgcn_mfma_f32_16x16x32_bf16(afrag[1], bf, z4, 0, 0, 0);
      f32x4 a2 = __builtin_amdgcn_mfma_f32_16x16x32_bf16(afrag[2], bf, z4, 0, 0, 0);
      f32x4 a3 = __builtin_amdgcn_mfma_f32_16x16x32_bf16(afrag[3], bf, z4, 0, 0, 0);
      // exact: exists row with a - 0.5*sq_row > 0.5*sq_col - MARG/2  <=>  d2_32 < MARG
      float m0 = fmaxf(fmaxf(a0[0] - hh[0][0], a0[1] - hh[0][1]),
                       fmaxf(a0[2] - hh[0][2], a0[3] - hh[0][3]));
      float m1 = fmaxf(fmaxf(a1[0] - hh[1][0], a1[1] - hh[1][1]),
                       fmaxf(a1[2] - hh[1][2], a1[3] - hh[1][3]));
      float m2 = fmaxf(fmaxf(a2[0] - hh[2][0], a2[1] - hh[2][1]),
                       fmaxf(a2[2] - hh[2][2], a2[3] - hh[2][3]));
      float m3 = fmaxf(fmaxf(a3[0] - hh[3][0], a3[1] - hh[3][1]),
                       fmaxf(a3[2] - hh[3][2], a3[3] - hh[3][3]));
      float m = fmaxf(fmaxf(m0, m1), fmaxf(m2, m3));
      if (__ballot(m > thrc[e])) hitmask |= (1u << e);
    }

  // ---- cold: only hit tiles (compact, single copy of capture code) ----
  if (hitmask) {
#pragma unroll 1
    for (int e = 0; e < 16; ++e) {
      if (!(hitmask & (1u << e))) continue;
      int cc = e >> 2, tc = e & 3;
      int rl = cc * 64 + tc * 16 + arow;
      short8 bf = *(const short8*)&sB[rl * 4 + (q ^ (rl & 3))];
      int colpt = cbase + cc * 64 + tc * 16 + arow;
      float scv = s32b[colpt];
      f32x4 acc[4];
#pragma unroll
      for (int tr = 0; tr < 4; ++tr)
        acc[tr] = __builtin_amdgcn_mfma_f32_16x16x32_bf16(afrag[tr], bf, z4, 0, 0, 0);
#pragma unroll
      for (int tr = 0; tr < 4; ++tr)
#pragma unroll
        for (int rg = 0; rg < 4; ++rg) {
          float d2 = srq[tr][rg] + scv - 2.f * acc[tr][rg];
          if (d2 < MARG) {
            int rowpt = rowbase + tr * 16 + (q << 2) + rg;
            int gr = b * NPTS + rowpt;
            union { float f; unsigned u; } cv; cv.f = d2 + 16.f;  // monotone bits
            unsigned kb = cv.u & 0xFFFFE000u;
            unsigned slot = atomicAdd(&cnt[gr], 1u);
            if (slot < CAP) cand[gr * CAP + slot] = kb | (unsigned)colpt;
            if (slot == 1u) {                 // 1->2 transition: row becomes coupled
              int ls = atomicAdd(lctr, 1);
              if (ls < MAXM) list[ls] = gr;
            }
            if (band != seg) {
              int gc = b * NPTS + colpt;
              unsigned slot2 = atomicAdd(&cnt[gc], 1u);
              if (slot2 < CAP) cand[gc * CAP + slot2] = kb | (unsigned)rowpt;
              if (slot2 == 1u) {
                int ls2 = atomicAdd(lctr, 1);
                if (ls2 < MAXM) list[ls2] = gc;
              }
            }
          }
        }
    }
  }
}

// ---------------- K3_fused: decoupled rows -> final out ; coupled rows -> refine ----
// 64 blocks x 256. cnt<=1: u <- lg - sigm(u) (w_self=1 exactly), 5x, write out, done.
// cnt>1 (~300 rows): sort candidates, exact-f32 d2, write Wbuf/IDX for kt_iter.
__global__ __launch_bounds__(256) void k3_fused(
    const float* __restrict__ f32f, const float* __restrict__ sq,
    const unsigned* __restrict__ cnt, const unsigned* __restrict__ cand,
    float* __restrict__ Wbuf, int* __restrict__ IDXb,
    const float* __restrict__ logits, float* __restrict__ out) {
  int r = blockIdx.x * 256 + threadIdx.x;
  int b = r >> 13;
  unsigned count = cnt[r];
  if (count <= 1u) {
    float lg = logits[r];
    float u = lg;
#pragma unroll
    for (int it = 0; it < 5; ++it) u = lg - sigm(u);
    out[r] = sigm(u);
    return;
  }
  if (count > CAP) count = CAP;

  unsigned k[CAP];
#pragma unroll
  for (int j = 0; j < CAP; ++j)
    k[j] = (j < (int)count) ? cand[r * CAP + j] : 0xFFFFFFFFu;
#pragma unroll
  for (int a = 0; a < CAP - 1; ++a)
#pragma unroll
    for (int c = 0; c < CAP - 1; ++c) {
      unsigned lo = min(k[c], k[c + 1]);
      unsigned hi = max(k[c], k[c + 1]);
      k[c] = lo; k[c + 1] = hi;
    }

  float fr[64];
  const f32x4* fr4 = (const f32x4*)(f32f + (size_t)r * 64);
#pragma unroll
  for (int j = 0; j < 16; ++j) {
    f32x4 v = fr4[j];
    fr[4 * j] = v[0]; fr[4 * j + 1] = v[1]; fr[4 * j + 2] = v[2]; fr[4 * j + 3] = v[3];
  }
  float sqr = sq[r];
  int nsel = (int)count < KNB ? (int)count : KNB;
#pragma unroll
  for (int kk = 0; kk < KNB; ++kk) {
    float w = 0.f;
    int gi = r;
    if (kk < nsel) {
      int col = (int)(k[kk] & 8191u);
      gi = b * NPTS + col;
      const float* fm = f32f + (size_t)gi * 64;
      float dot = 0.f;
#pragma unroll
      for (int d = 0; d < 64; ++d) dot = fmaf(fr[d], fm[d], dot); // matches sq chain -> self d2==0
      float d2 = sqr + sq[gi] - 2.f * dot;
      w = expf(-d2);
    }
    Wbuf[(size_t)r * KNB + kk] = w;
    IDXb[(size_t)r * KNB + kk] = gi;
  }
}

// ---------------- KT_iter: 5 coupled iterations over the ~300-row subgraph ----
// Graph is symmetric (mirror capture) => neighbors of coupled rows are coupled.
// 1 block x 1024; reads ONLY the compact list built in k2 (no 16K cnt scan);
// qs in LDS indexed by global row; W/IDX L2-hot.
__global__ __launch_bounds__(1024) void kt_iter(
    const int* __restrict__ lctr, const int* __restrict__ list,
    const float* __restrict__ Wbuf, const int* __restrict__ IDXb,
    const float* __restrict__ logits, float* __restrict__ out) {
  __shared__ float qs[NTOT];                // 64 KB (indexed by global row)
  __shared__ int slist[MAXM];               // 32 KB
  __shared__ float su[MAXM];                // 32 KB
  int t = threadIdx.x;
  int nm = *lctr; if (nm > MAXM) nm = MAXM;

#pragma unroll 1
  for (int k = t; k < nm; k += 1024) {
    int r = list[k];
    slist[k] = r;
    qs[r] = sigm(logits[r]);
  }
  __syncthreads();

  for (int it = 0; it < 5; ++it) {
#pragma unroll 1
    for (int k = t; k < nm; k += 1024) {
      int r = slist[k];
      float msg = 0.f;
      const float* wp = Wbuf + (size_t)r * KNB;
      const int* ip = IDXb + (size_t)r * KNB;
#pragma unroll
      for (int kk = 0; kk < KNB; ++kk) msg = fmaf(wp[kk], qs[ip[kk]], msg);
      su[k] = logits[r] - msg;
    }
    __syncthreads();
#pragma unroll 1
    for (int k = t; k < nm; k += 1024) qs[slist[k]] = sigm(su[k]);
    __syncthreads();
  }
#pragma unroll 1
  for (int k = t; k < nm; k += 1024) out[slist[k]] = sigm(su[k]);
}

// ---------------- launch ----------------
extern "C" void kernel_launch(void* const* d_in, const int* in_sizes, int n_in,
                              void* d_out, int out_size, void* d_ws, size_t ws_size,
                              hipStream_t stream) {
  const float* logits = (const float*)d_in[0]; // [2][8192]
  const float* p      = (const float*)d_in[1]; // [2][64][8192]
  const float* W1     = (const float*)d_in[2];
  const float* b1     = (const float*)d_in[3];
  const float* W2     = (const float*)d_in[4];
  const float* b2     = (const float*)d_in[5];
  float* out = (float*)d_out;                  // [2][8192]

  char* ws = (char*)d_ws;
  float* f32f = (float*)ws;                                        // NTOT*64 f
  unsigned short* fpre = (unsigned short*)(f32f + (size_t)NTOT * 64); // NTOT*32 bf16
  float* sq = (float*)(fpre + (size_t)NTOT * 32);                  // NTOT f
  float* sq32 = sq + NTOT;                                         // NTOT f
  unsigned* cnt = (unsigned*)(sq32 + NTOT);                        // NTOT u32
  unsigned* cand = cnt + NTOT;                                     // NTOT*CAP u32
  float* Wbuf = (float*)(cand + (size_t)NTOT * CAP);               // NTOT*11 f
  int* IDX = (int*)(Wbuf + (size_t)NTOT * KNB);                    // NTOT*11 i32
  int* lctr = IDX + (size_t)NTOT * KNB;                            // 1 i32
  int* list = lctr + 1;                                            // MAXM i32

  k1_encode<<<256, 256, 0, stream>>>(p, W1, b1, W2, b2, f32f, fpre, sq, sq32, cnt, lctr);
  k2_gram_select<<<1056, 256, 0, stream>>>(fpre, sq32, cnt, cand, lctr, list);
  k3_fused<<<64, 256, 0, stream>>>(f32f, sq, cnt, cand, Wbuf, IDX, logits, out);
  kt_iter<<<1, 1024, 0, stream>>>(lctr, list, Wbuf, IDX, logits, out);
}

// Round 2
// 107.967 us; speedup vs baseline: 1.0816x; 1.0358x over previous
//
#include <hip/hip_runtime.h>

#define NPTS 8192
#define NTOT 16384
#define KNB 11
#define CAP 16
#define MARG 9.0f
#define MAXM 8192

typedef __attribute__((ext_vector_type(8))) short short8;
typedef __attribute__((ext_vector_type(4))) float f32x4;

__device__ __forceinline__ unsigned short f2bf(float x) {
  union { float f; unsigned u; } v; v.f = x;
  unsigned r = v.u + 0x7FFFu + ((v.u >> 16) & 1u);
  return (unsigned short)(r >> 16);
}

__device__ __forceinline__ float sigm(float x) { return 1.f / (1.f + expf(-x)); }

// ---------------- K1: f = (p^T*W1 + b1)*W2 + b2 ; sq/sq32 ; bf16 prefilter copy ----
// 256 blocks x 256 threads: 64 points/block, wave w handles dims e0=w*16..+16.
// Two chained 64x64 GEMMs; t staged through a +1-padded LDS transpose.
// W1/W2 rows are wave-uniform -> s_load path. Also zeroes cnt and lctr.
__global__ __launch_bounds__(256) void k1_encode(
    const float* __restrict__ p,      // [2][64][NPTS]
    const float* __restrict__ W1,     // [64][64]
    const float* __restrict__ b1,     // [64]
    const float* __restrict__ W2,     // [64][64]
    const float* __restrict__ b2,     // [64]
    float* __restrict__ f32f,         // [NTOT][64]
    unsigned short* __restrict__ fpre,// [NTOT][32] bf16 (dims 0..31)
    float* __restrict__ sq,           // [NTOT] full 64-dim |f|^2
    float* __restrict__ sq32,         // [NTOT] dims 0..31 |f|^2
    unsigned* __restrict__ cnt,       // [NTOT] candidate counters (zeroed here)
    int* __restrict__ lctr) {         // coupled-list counter (zeroed here)
  __shared__ float sp[64 * 64];       // 16 KB: sp[d*64 + n_local]
  __shared__ float st[64 * 65];       // 16.25 KB: st[n_local*65 + d] (+1 pad)
  __shared__ float sPart[4][64];
  int t = threadIdx.x, lane = t & 63;
  int w = __builtin_amdgcn_readfirstlane(t >> 6);
  int e0 = w * 16;                          // wave-uniform -> scalar loads
  int base = blockIdx.x * 64;
  int b = base >> 13, n0 = base & (NPTS - 1);
  const float* pb = p + (size_t)b * 64 * NPTS + n0;

  if (w == 0) cnt[base + lane] = 0u;        // 256 blocks x 64 = all NTOT rows
  if (base == 0 && t == 0) *lctr = 0;

  // stage p tile: 64 d-rows x 64 points, coalesced uint4
  int row = t >> 4, chunk = t & 15;
#pragma unroll
  for (int k = 0; k < 4; ++k) {
    int r = k * 16 + row;
    uint4 v = *(const uint4*)(pb + (size_t)r * NPTS + chunk * 4);
    *(uint4*)(sp + r * 64 + chunk * 4) = v;
  }
  __syncthreads();

  // GEMM1: t[n][e] = b1[e] + sum_d p[d][n]*W1[d][e]
  float tt[16];
#pragma unroll
  for (int j = 0; j < 16; ++j) tt[j] = b1[e0 + j];
#pragma unroll 8
  for (int d = 0; d < 64; ++d) {
    float pd = sp[d * 64 + lane];
#pragma unroll
    for (int j = 0; j < 16; ++j)
      tt[j] = fmaf(pd, W1[d * 64 + e0 + j], tt[j]);
  }
  // transpose t into LDS: st[point][dim], pad 65 -> conflict-free both ways
#pragma unroll
  for (int j = 0; j < 16; ++j) st[lane * 65 + e0 + j] = tt[j];
  __syncthreads();

  // GEMM2: f[n][e] = b2[e] + sum_d t[n][d]*W2[d][e]
  float f[16];
#pragma unroll
  for (int j = 0; j < 16; ++j) f[j] = b2[e0 + j];
#pragma unroll 8
  for (int d = 0; d < 64; ++d) {
    float td = st[lane * 65 + d];
#pragma unroll
    for (int j = 0; j < 16; ++j)
      f[j] = fmaf(td, W2[d * 64 + e0 + j], f[j]);
  }

  float s = 0.f;
#pragma unroll
  for (int j = 0; j < 16; ++j) s = fmaf(f[j], f[j], s);
  sPart[w][lane] = s;
  __syncthreads();
  if (w == 0) {
    float s32 = sPart[0][lane] + sPart[1][lane];
    float s64 = s32 + (sPart[2][lane] + sPart[3][lane]);
    sq32[base + lane] = s32;
    sq[base + lane] = s64;
  }

  f32x4* o4 = (f32x4*)(f32f + (size_t)(base + lane) * 64 + e0);
#pragma unroll
  for (int jj = 0; jj < 4; ++jj) {
    f32x4 v; v[0] = f[4 * jj]; v[1] = f[4 * jj + 1]; v[2] = f[4 * jj + 2]; v[3] = f[4 * jj + 3];
    o4[jj] = v;
  }
  if (w < 2) {                               // dims 0..31 -> bf16 prefilter
    unsigned* ob = (unsigned*)(fpre + (size_t)(base + lane) * 32 + e0);
#pragma unroll
    for (int jj = 0; jj < 8; ++jj) {
      unsigned lo = f2bf(f[2 * jj]);
      unsigned hi = f2bf(f[2 * jj + 1]);
      ob[jj] = lo | (hi << 16);
    }
  }
}

// ---------------- K2: 32-dim prefilter Gram, triangle-symmetric ----
// 1056 blocks = 2 x 528 (lower-triangle incl diag of 32x32 256-blocks).
// Hot: per tile 1 ds_read + 4 MFMA (C = -0.5*sq_row folded in!) + max-tree -> SGPR hitmask.
// Cold (once, after loop): recompute only hit tiles (diag: 4/16; off-diag: ~never).
// Row's 1->2 cnt transition appends it to the compact coupled list.
__global__ __launch_bounds__(256) void k2_gram_select(
    const unsigned short* __restrict__ fpre, // [NTOT][32]
    const float* __restrict__ sq32,          // [NTOT]
    unsigned* __restrict__ cnt,              // [NTOT]
    unsigned* __restrict__ cand,             // [NTOT][CAP]
    int* __restrict__ lctr,                  // coupled-list counter
    int* __restrict__ list) {                // [MAXM] coupled rows (global ids)
  __shared__ uint4 sB[1024];                 // 16 KB panel, XOR-swizzled
  int bid = blockIdx.x;
  int b = (bid >= 528) ? 1 : 0;
  int rem = bid - b * 528;
  int band = (int)((sqrtf(8.f * (float)rem + 1.f) - 1.f) * 0.5f);
  if (((band + 1) * (band + 2)) / 2 <= rem) band++;
  else if ((band * (band + 1)) / 2 > rem) band--;
  int seg = rem - (band * (band + 1)) / 2;

  int t = threadIdx.x;
  int lane = t & 63;
  int arow = lane & 15;
  int q = lane >> 4;
  int wave = t >> 6;
  int rowbase = band * 256 + wave * 64;
  int cbase = seg * 256;
  const unsigned short* fb = fpre + (size_t)b * NPTS * 32;
  const float* s32b = sq32 + b * NPTS;

  // ---- prologue: all global loads, then ONE barrier ----
  const uint4* gsrc = (const uint4*)fb + (size_t)seg * 1024;
  uint4 v[4];
#pragma unroll
  for (int k = 0; k < 4; ++k) v[k] = gsrc[t + k * 256];

  short8 afrag[4];
#pragma unroll
  for (int tr = 0; tr < 4; ++tr)
    afrag[tr] = *(const short8*)(fb + (size_t)(rowbase + tr * 16 + arow) * 32 + q * 8);

  f32x4 srq[4], nh[4];                       // nh = -0.5*sq_row -> MFMA C operand
#pragma unroll
  for (int tr = 0; tr < 4; ++tr) {
    srq[tr] = *(const f32x4*)(s32b + rowbase + tr * 16 + (q << 2));
    nh[tr] = -0.5f * srq[tr];
  }
  float thrc[16];                            // per-lane column threshold
#pragma unroll
  for (int cc = 0; cc < 4; ++cc)
#pragma unroll
    for (int tc = 0; tc < 4; ++tc)
      thrc[cc * 4 + tc] = 0.5f * s32b[cbase + cc * 64 + tc * 16 + arow] - 0.5f * MARG;

#pragma unroll
  for (int k = 0; k < 4; ++k) {
    int c = t + k * 256;
    int r = c >> 2, qq = c & 3;
    sB[r * 4 + (qq ^ (r & 3))] = v[k];
  }
  __syncthreads();   // the ONLY barrier

  // ---- hot pass: MFMA (acc = a - 0.5*sq_row) + max-tree margin test ----
  unsigned hitmask = 0u;
#pragma unroll
  for (int cc = 0; cc < 4; ++cc)
#pragma unroll
    for (int tc = 0; tc < 4; ++tc) {
      int e = cc * 4 + tc;
      int rl = cc * 64 + tc * 16 + arow;
      short8 bf = *(const short8*)&sB[rl * 4 + (q ^ (rl & 3))];
      f32x4 a0 = __builtin_amdgcn_mfma_f32_16x16x32_bf16(afrag[0], bf, nh[0], 0, 0, 0);
      f32x4 a1 = __builtin_amdgcn_mfma_f32_16x16x32_bf16(afrag[1], bf, nh[1], 0, 0, 0);
      f32x4 a2 = __builtin_amdgcn_mfma_f32_16x16x32_bf16(afrag[2], bf, nh[2], 0, 0, 0);
      f32x4 a3 = __builtin_amdgcn_mfma_f32_16x16x32_bf16(afrag[3], bf, nh[3], 0, 0, 0);
      // exact: exists row with a - 0.5*sq_row > 0.5*sq_col - MARG/2  <=>  d2_32 < MARG
      float m0 = fmaxf(fmaxf(a0[0], a0[1]), fmaxf(a0[2], a0[3]));
      float m1 = fmaxf(fmaxf(a1[0], a1[1]), fmaxf(a1[2], a1[3]));
      float m2 = fmaxf(fmaxf(a2[0], a2[1]), fmaxf(a2[2], a2[3]));
      float m3 = fmaxf(fmaxf(a3[0], a3[1]), fmaxf(a3[2], a3[3]));
      float m = fmaxf(fmaxf(m0, m1), fmaxf(m2, m3));
      if (__ballot(m > thrc[e])) hitmask |= (1u << e);
    }

  // ---- cold: only hit tiles (compact, single copy of capture code) ----
  if (hitmask) {
#pragma unroll 1
    for (int e = 0; e < 16; ++e) {
      if (!(hitmask & (1u << e))) continue;
      int cc = e >> 2, tc = e & 3;
      int rl = cc * 64 + tc * 16 + arow;
      short8 bf = *(const short8*)&sB[rl * 4 + (q ^ (rl & 3))];
      int colpt = cbase + cc * 64 + tc * 16 + arow;
      float scv = s32b[colpt];
      f32x4 acc[4];
#pragma unroll
      for (int tr = 0; tr < 4; ++tr)
        acc[tr] = __builtin_amdgcn_mfma_f32_16x16x32_bf16(afrag[tr], bf, nh[tr], 0, 0, 0);
#pragma unroll
      for (int tr = 0; tr < 4; ++tr)
#pragma unroll
        for (int rg = 0; rg < 4; ++rg) {
          float d2 = scv - 2.f * acc[tr][rg];      // = sq_row + sq_col - 2*dot
          if (d2 < MARG) {
            int rowpt = rowbase + tr * 16 + (q << 2) + rg;
            int gr = b * NPTS + rowpt;
            union { float f; unsigned u; } cv; cv.f = d2 + 16.f;  // monotone bits
            unsigned kb = cv.u & 0xFFFFE000u;
            unsigned slot = atomicAdd(&cnt[gr], 1u);
            if (slot < CAP) cand[gr * CAP + slot] = kb | (unsigned)colpt;
            if (slot == 1u) {                 // 1->2 transition: row becomes coupled
              int ls = atomicAdd(lctr, 1);
              if (ls < MAXM) list[ls] = gr;
            }
            if (band != seg) {
              int gc = b * NPTS + colpt;
              unsigned slot2 = atomicAdd(&cnt[gc], 1u);
              if (slot2 < CAP) cand[gc * CAP + slot2] = kb | (unsigned)rowpt;
              if (slot2 == 1u) {
                int ls2 = atomicAdd(lctr, 1);
                if (ls2 < MAXM) list[ls2] = gc;
              }
            }
          }
        }
    }
  }
}

// ---------------- K3_final: ONE launch for everything after k2 ----
// Blocks 0..63: decoupled rows (cnt<=1): u <- lg - sigm(u), 5x, write out.
// Block 64: the coupled subgraph (~300 rows). Sort candidates, exact-f32 d2 ->
// Wbuf/IDX (global, L2-hot, block-visible after __syncthreads), then 5
// mean-field iterations with qs in LDS, write out. Runs CONCURRENTLY with
// the decoupled blocks (disjoint output rows).
__global__ __launch_bounds__(256) void k3_final(
    const float* __restrict__ f32f, const float* __restrict__ sq,
    const unsigned* __restrict__ cnt, const unsigned* __restrict__ cand,
    const int* __restrict__ lctr, const int* __restrict__ list,
    float* __restrict__ Wbuf, int* __restrict__ IDXb,
    const float* __restrict__ logits, float* __restrict__ out) {
  __shared__ float qs[NTOT];                // 64 KB (indexed by global row)
  __shared__ int slist[MAXM];               // 32 KB
  __shared__ float su[MAXM];                // 32 KB
  int t = threadIdx.x;
  int bid = blockIdx.x;

  if (bid < 64) {                           // ---- decoupled fast path ----
    int r = bid * 256 + t;
    unsigned count = cnt[r];
    if (count <= 1u) {
      float lg = logits[r];
      float u = lg;
#pragma unroll
      for (int it = 0; it < 5; ++it) u = lg - sigm(u);
      out[r] = sigm(u);
    }
    return;
  }

  // ---- block 64: coupled subgraph ----
  int nm = *lctr; if (nm > MAXM) nm = MAXM;

#pragma unroll 1
  for (int k = t; k < nm; k += 256) {
    int r = list[k];
    slist[k] = r;
    qs[r] = sigm(logits[r]);
  }
  __syncthreads();

  // build Wbuf/IDX: one coupled row per thread (wraps)
#pragma unroll 1
  for (int k = t; k < nm; k += 256) {
    int r = slist[k];
    int b = r >> 13;
    unsigned count = cnt[r];
    if (count > CAP) count = CAP;

    unsigned kc[CAP];
#pragma unroll
    for (int j = 0; j < CAP; ++j)
      kc[j] = (j < (int)count) ? cand[r * CAP + j] : 0xFFFFFFFFu;
#pragma unroll
    for (int a = 0; a < CAP - 1; ++a)
#pragma unroll
      for (int c = 0; c < CAP - 1; ++c) {
        unsigned lo = min(kc[c], kc[c + 1]);
        unsigned hi = max(kc[c], kc[c + 1]);
        kc[c] = lo; kc[c + 1] = hi;
      }

    float fr[64];
    const f32x4* fr4 = (const f32x4*)(f32f + (size_t)r * 64);
#pragma unroll
    for (int j = 0; j < 16; ++j) {
      f32x4 v = fr4[j];
      fr[4 * j] = v[0]; fr[4 * j + 1] = v[1]; fr[4 * j + 2] = v[2]; fr[4 * j + 3] = v[3];
    }
    float sqr = sq[r];
    int nsel = (int)count < KNB ? (int)count : KNB;
#pragma unroll
    for (int kk = 0; kk < KNB; ++kk) {
      float w = 0.f;
      int gi = r;
      if (kk < nsel) {
        int col = (int)(kc[kk] & 8191u);
        gi = b * NPTS + col;
        const float* fm = f32f + (size_t)gi * 64;
        float dot = 0.f;
#pragma unroll
        for (int d = 0; d < 64; ++d) dot = fmaf(fr[d], fm[d], dot); // matches sq chain -> self d2==0
        float d2 = sqr + sq[gi] - 2.f * dot;
        w = expf(-d2);
      }
      Wbuf[(size_t)r * KNB + kk] = w;
      IDXb[(size_t)r * KNB + kk] = gi;
    }
  }
  __syncthreads();   // global writes visible block-wide after barrier

  for (int it = 0; it < 5; ++it) {
#pragma unroll 1
    for (int k = t; k < nm; k += 256) {
      int r = slist[k];
      float msg = 0.f;
      const float* wp = Wbuf + (size_t)r * KNB;
      const int* ip = IDXb + (size_t)r * KNB;
#pragma unroll
      for (int kk = 0; kk < KNB; ++kk) msg = fmaf(wp[kk], qs[ip[kk]], msg);
      su[k] = logits[r] - msg;
    }
    __syncthreads();
#pragma unroll 1
    for (int k = t; k < nm; k += 256) qs[slist[k]] = sigm(su[k]);
    __syncthreads();
  }
#pragma unroll 1
  for (int k = t; k < nm; k += 256) out[slist[k]] = sigm(su[k]);
}

// ---------------- launch ----------------
extern "C" void kernel_launch(void* const* d_in, const int* in_sizes, int n_in,
                              void* d_out, int out_size, void* d_ws, size_t ws_size,
                              hipStream_t stream) {
  const float* logits = (const float*)d_in[0]; // [2][8192]
  const float* p      = (const float*)d_in[1]; // [2][64][8192]
  const float* W1     = (const float*)d_in[2];
  const float* b1     = (const float*)d_in[3];
  const float* W2     = (const float*)d_in[4];
  const float* b2     = (const float*)d_in[5];
  float* out = (float*)d_out;                  // [2][8192]

  char* ws = (char*)d_ws;
  float* f32f = (float*)ws;                                        // NTOT*64 f
  unsigned short* fpre = (unsigned short*)(f32f + (size_t)NTOT * 64); // NTOT*32 bf16
  float* sq = (float*)(fpre + (size_t)NTOT * 32);                  // NTOT f
  float* sq32 = sq + NTOT;                                         // NTOT f
  unsigned* cnt = (unsigned*)(sq32 + NTOT);                        // NTOT u32
  unsigned* cand = cnt + NTOT;                                     // NTOT*CAP u32
  float* Wbuf = (float*)(cand + (size_t)NTOT * CAP);               // NTOT*11 f
  int* IDX = (int*)(Wbuf + (size_t)NTOT * KNB);                    // NTOT*11 i32
  int* lctr = IDX + (size_t)NTOT * KNB;                            // 1 i32
  int* list = lctr + 1;                                            // MAXM i32

  k1_encode<<<256, 256, 0, stream>>>(p, W1, b1, W2, b2, f32f, fpre, sq, sq32, cnt, lctr);
  k2_gram_select<<<1056, 256, 0, stream>>>(fpre, sq32, cnt, cand, lctr, list);
  k3_final<<<65, 256, 0, stream>>>(f32f, sq, cnt, cand, lctr, list, Wbuf, IDX, logits, out);
}